// Round 3
// baseline (179.877 us; speedup 1.0000x reference)
//
#include <hip/hip_runtime.h>
#include <stdint.h>

#define BDIM 4
#define CDIM 512
#define HDIM 128
#define WDIM 128
#define HWDIM (HDIM*WDIM)
#define SADMP 16
#define BHW 8
#define KKP 256

using short8 = __attribute__((ext_vector_type(8))) short;
using f32x4  = __attribute__((ext_vector_type(4))) float;

__device__ __forceinline__ unsigned short f2bf(float f) {
    unsigned u = __float_as_uint(f);
    unsigned r = (u + 0x7fffu + ((u >> 16) & 1u)) >> 16;
    return (unsigned short)r;
}
__device__ __forceinline__ float bf2f(unsigned short h) {
    return __uint_as_float(((unsigned)h) << 16);
}
__device__ __forceinline__ unsigned int ordf(float f) {
    unsigned u = __float_as_uint(f);
    return (u & 0x80000000u) ? ~u : (u | 0x80000000u);
}

// ---------------- K1: resp[b][hw] = sum_c A[b][c][hw] ----------------
__global__ void resp_kernel(const float* __restrict__ A, float* __restrict__ resp) {
    int gid = blockIdx.x * blockDim.x + threadIdx.x;
    int b = gid / HWDIM, hw = gid % HWDIM;
    const float* p = A + (size_t)b * CDIM * HWDIM + hw;
    float s0 = 0.f, s1 = 0.f, s2 = 0.f, s3 = 0.f;
    #pragma unroll 4
    for (int c = 0; c < CDIM; c += 4) {
        s0 += p[(size_t)(c + 0) * HWDIM];
        s1 += p[(size_t)(c + 1) * HWDIM];
        s2 += p[(size_t)(c + 2) * HWDIM];
        s3 += p[(size_t)(c + 3) * HWDIM];
    }
    resp[gid] = (s0 + s1) + (s2 + s3);
}

// ---------------- K2: per-window argmax (first occurrence) ----------------
__global__ void argmax_kernel(const float* __restrict__ resp, int* __restrict__ kp) {
    int win = blockIdx.x;                 // b*K + k
    int b = win / KKP, k = win % KKP;
    int bi = k / SADMP, bj = k % SADMP;
    int l = threadIdx.x;                  // 0..63 == loc
    int r = l >> 3, c = l & 7;
    int h = bi * BHW + r, w = bj * BHW + c;
    float v = resp[b * HWDIM + h * WDIM + w];
    int idx = l;
    #pragma unroll
    for (int off = 32; off; off >>= 1) {
        float ov = __shfl_down(v, off);
        int   oi = __shfl_down(idx, off);
        if (ov > v || (ov == v && oi < idx)) { v = ov; idx = oi; }
    }
    if (l == 0) {
        int row = bi * BHW + (idx >> 3);
        int col = bj * BHW + (idx & 7);
        kp[win] = row * WDIM + col;
    }
}

// ---------------- K3: gather + hi/lo convert into MFMA-fragment order + dn ----------------
__global__ void convert_kernel(const float* __restrict__ A, const int* __restrict__ kp,
                               uint4* __restrict__ frag, float* __restrict__ dn) {
    int blk = blockIdx.x;                 // b*16 + mf
    int b = blk >> 4, mf = blk & 15;
    int t = threadIdx.x;                  // 0..255
    int l = t & 63, q0 = t >> 6;
    int ml = l & 15;
    int m  = mf * 16 + ml;
    int cg = (l >> 4) * 8;
    int idx = kp[b * KKP + m];
    const float* Ab = A + (size_t)b * CDIM * HWDIM + idx;
    float sq = 0.f;
    #pragma unroll
    for (int qq = 0; qq < 4; qq++) {
        int q = q0 * 4 + qq;
        unsigned hi[4], lo[4];
        #pragma unroll
        for (int jj = 0; jj < 4; jj++) {
            int c0 = q * 32 + cg + jj * 2;
            float v0 = Ab[(size_t)c0 * HWDIM];
            float v1 = Ab[(size_t)(c0 + 1) * HWDIM];
            sq = fmaf(v0, v0, sq);
            sq = fmaf(v1, v1, sq);
            unsigned short h0 = f2bf(v0), h1 = f2bf(v1);
            unsigned short l0 = f2bf(v0 - bf2f(h0)), l1 = f2bf(v1 - bf2f(h1));
            hi[jj] = (unsigned)h0 | ((unsigned)h1 << 16);
            lo[jj] = (unsigned)l0 | ((unsigned)l1 << 16);
        }
        frag[((size_t)b * 2 + 0) * 16384 + mf * 1024 + q * 64 + l] = make_uint4(hi[0], hi[1], hi[2], hi[3]);
        frag[((size_t)b * 2 + 1) * 16384 + mf * 1024 + q * 64 + l] = make_uint4(lo[0], lo[1], lo[2], lo[3]);
    }
    __shared__ float red[16][17];
    red[ml][(l >> 4) * 4 + q0] = sq;
    __syncthreads();
    if (t < 16) {
        float s = 0.f;
        #pragma unroll
        for (int i = 0; i < 16; i++) s += red[t][i];
        dn[b * KKP + mf * 16 + t] = s;
    }
}

// ---------------- K4: MFMA dist + argmin ----------------
// BM=256 (all keypoints), BN=64, BK=64/step, 8 steps, bf16 hi/lo 3-term.
// B staged in LDS in EXACT MFMA-fragment order (contiguous 1KB fragments ->
// conflict-free b128 reads/writes), double-buffered, one barrier per step.
__global__ __launch_bounds__(512) void dist_mfma_kernel(
    const uint4* __restrict__ fragA, const float* __restrict__ fb,
    const float* __restrict__ dn, unsigned long long* __restrict__ minkey)
{
    const int n0 = blockIdx.x * 64;
    const int b  = blockIdx.y;
    const int t  = threadIdx.x;
    const int l  = t & 63;
    const int w  = t >> 6;                // wave 0..7: rows w*32 .. w*32+31

    // [buf][term][ch][nf][lane*16B] : 2*2*2*4*1024 = 32 KB
    __shared__ uint4 sbRaw[2048];
    __shared__ float bnp[8][64];
    __shared__ float bnf[64];
    __shared__ float dnl[256];
    char* sbBase = (char*)sbRaw;

    if (t < 256) dnl[t] = dn[b * KKP + t];

    f32x4 acc[2][4] = {};                 // [mfl][nf]
    const float* fbp = fb + (size_t)b * CDIM * HWDIM + n0 + l;
    float bnacc = 0.f;

    // this thread's LDS write slot (fragment order):
    // term0 base + ch(w>>2)*4096 + nf(l>>4)*1024 + slot((w&3)*16+(l&15))*16
    const int wbase = ((w >> 2) << 12) + ((l >> 4) << 10) + ((((w & 3) << 4) + (l & 15)) << 4);

    const short8* fA = (const short8*)fragA;
    const size_t baseHi = ((size_t)b * 2 + 0) * 16384;
    const size_t baseLo = ((size_t)b * 2 + 1) * 16384;
    const int cbase = w * 8;

    float v[2][8];

    // prologue: load step0, convert+write buf0, issue step1 loads
    #pragma unroll
    for (int i = 0; i < 8; i++) v[0][i] = fbp[(size_t)(cbase + i) * HWDIM];
    {
        unsigned hi[4], lo[4];
        #pragma unroll
        for (int jj = 0; jj < 4; jj++) {
            float v0 = v[0][jj * 2], v1 = v[0][jj * 2 + 1];
            bnacc = fmaf(v0, v0, bnacc);
            bnacc = fmaf(v1, v1, bnacc);
            unsigned short h0 = f2bf(v0), h1 = f2bf(v1);
            unsigned short l0 = f2bf(v0 - bf2f(h0)), l1 = f2bf(v1 - bf2f(h1));
            hi[jj] = (unsigned)h0 | ((unsigned)h1 << 16);
            lo[jj] = (unsigned)l0 | ((unsigned)l1 << 16);
        }
        *(uint4*)(sbBase + wbase)        = make_uint4(hi[0], hi[1], hi[2], hi[3]);
        *(uint4*)(sbBase + wbase + 8192) = make_uint4(lo[0], lo[1], lo[2], lo[3]);
    }
    #pragma unroll
    for (int i = 0; i < 8; i++) v[1][i] = fbp[(size_t)(64 + cbase + i) * HWDIM];
    __syncthreads();

    #pragma unroll
    for (int s = 0; s < 8; s++) {
        const int cur = s & 1;
        // (a) issue loads for step s+2 into the reg set just freed
        if (s < 6) {
            #pragma unroll
            for (int i = 0; i < 8; i++)
                v[cur][i] = fbp[(size_t)((s + 2) * 64 + cbase + i) * HWDIM];
        }
        // (b) convert step s+1 -> write buf[cur^1]
        if (s < 7) {
            unsigned hi[4], lo[4];
            #pragma unroll
            for (int jj = 0; jj < 4; jj++) {
                float v0 = v[(s + 1) & 1][jj * 2], v1 = v[(s + 1) & 1][jj * 2 + 1];
                bnacc = fmaf(v0, v0, bnacc);
                bnacc = fmaf(v1, v1, bnacc);
                unsigned short h0 = f2bf(v0), h1 = f2bf(v1);
                unsigned short l0 = f2bf(v0 - bf2f(h0)), l1 = f2bf(v1 - bf2f(h1));
                hi[jj] = (unsigned)h0 | ((unsigned)h1 << 16);
                lo[jj] = (unsigned)l0 | ((unsigned)l1 << 16);
            }
            char* wp = sbBase + (cur ^ 1) * 16384 + wbase;
            *(uint4*)(wp)        = make_uint4(hi[0], hi[1], hi[2], hi[3]);
            *(uint4*)(wp + 8192) = make_uint4(lo[0], lo[1], lo[2], lo[3]);
        }
        // (c) MFMA on buf[cur]
        #pragma unroll
        for (int ch = 0; ch < 2; ch++) {
            const int q = s * 2 + ch;
            short8 a_hi0 = fA[baseHi + (size_t)(w * 2 + 0) * 1024 + q * 64 + l];
            short8 a_hi1 = fA[baseHi + (size_t)(w * 2 + 1) * 1024 + q * 64 + l];
            short8 a_lo0 = fA[baseLo + (size_t)(w * 2 + 0) * 1024 + q * 64 + l];
            short8 a_lo1 = fA[baseLo + (size_t)(w * 2 + 1) * 1024 + q * 64 + l];
            const char* rp = sbBase + cur * 16384 + ch * 4096 + l * 16;
            __builtin_amdgcn_s_setprio(1);
            #pragma unroll
            for (int nf = 0; nf < 4; nf++) {
                short8 b_hi = *(const short8*)(rp + nf * 1024);
                short8 b_lo = *(const short8*)(rp + nf * 1024 + 8192);
                acc[0][nf] = __builtin_amdgcn_mfma_f32_16x16x32_bf16(a_hi0, b_hi, acc[0][nf], 0, 0, 0);
                acc[0][nf] = __builtin_amdgcn_mfma_f32_16x16x32_bf16(a_hi0, b_lo, acc[0][nf], 0, 0, 0);
                acc[0][nf] = __builtin_amdgcn_mfma_f32_16x16x32_bf16(a_lo0, b_hi, acc[0][nf], 0, 0, 0);
                acc[1][nf] = __builtin_amdgcn_mfma_f32_16x16x32_bf16(a_hi1, b_hi, acc[1][nf], 0, 0, 0);
                acc[1][nf] = __builtin_amdgcn_mfma_f32_16x16x32_bf16(a_hi1, b_lo, acc[1][nf], 0, 0, 0);
                acc[1][nf] = __builtin_amdgcn_mfma_f32_16x16x32_bf16(a_lo1, b_hi, acc[1][nf], 0, 0, 0);
            }
            __builtin_amdgcn_s_setprio(0);
        }
        __syncthreads();
    }

    // bn reduction
    bnp[w][l] = bnacc;
    __syncthreads();
    if (t < 64) {
        float s = 0.f;
        #pragma unroll
        for (int i = 0; i < 8; i++) s += bnp[i][t];
        bnf[t] = s;
    }
    __syncthreads();

    // epilogue: dist = dn - 2*cross + bn, packed argmin, atomicMin
    #pragma unroll
    for (int mfl = 0; mfl < 2; mfl++) {
        #pragma unroll
        for (int r = 0; r < 4; r++) {
            int m = w * 32 + mfl * 16 + (l >> 4) * 4 + r;
            float dnm = dnl[m];
            unsigned long long best = ~0ull;
            #pragma unroll
            for (int nf = 0; nf < 4; nf++) {
                int nloc = nf * 16 + (l & 15);
                float d = dnm - 2.f * acc[mfl][nf][r] + bnf[nloc];
                unsigned long long key = ((unsigned long long)ordf(d) << 32) | (unsigned)(n0 + nloc);
                if (key < best) best = key;
            }
            #pragma unroll
            for (int off = 1; off < 16; off <<= 1) {
                unsigned long long o = __shfl_xor(best, off);
                if (o < best) best = o;
            }
            if ((l & 15) == 0) atomicMin(&minkey[b * KKP + m], best);
        }
    }
}

// ---------------- K5: finalize ----------------
__global__ void finalize_kernel(const unsigned long long* __restrict__ minkey,
                                const int* __restrict__ kp,
                                float* __restrict__ out)
{
    int b = blockIdx.x;
    int k = threadIdx.x;
    unsigned long long key = minkey[b * KKP + k];
    unsigned n   = (unsigned)(key & 0xffffffffu);
    unsigned top = (unsigned)(key >> 32);
    unsigned fbits = (top & 0x80000000u) ? (top ^ 0x80000000u) : ~top;
    out[8 + b * KKP + k] = __uint_as_float(fbits);

    int idxA = kp[b * KKP + k];
    int rowA = idxA >> 7, colA = idxA & 127;
    int rowB = (int)(n >> 7), colB = (int)(n & 127);
    int drow = rowA - rowB, dcol = colA - colB;
    int code = (drow + 256) * 1024 + (dcol + 256);

    __shared__ int codes[KKP];
    __shared__ int keys[KKP];
    codes[k] = code;
    __syncthreads();
    int cnt = 0;
    for (int j = 0; j < KKP; j++) cnt += (codes[j] == code);
    keys[k] = cnt * 256 + (255 - k);
    __syncthreads();
    for (int s = 128; s; s >>= 1) {
        if (k < s) keys[k] = max(keys[k], keys[k + s]);
        __syncthreads();
    }
    if (k == 0) {
        int bestk = 255 - (keys[0] & 255);
        int bc = codes[bestk];
        int dr = bc / 1024 - 256, dc = bc % 1024 - 256;
        out[b * 2 + 0] = (float)dr;
        out[b * 2 + 1] = (float)dc;
    }
}

extern "C" void kernel_launch(void* const* d_in, const int* in_sizes, int n_in,
                              void* d_out, int out_size, void* d_ws, size_t ws_size,
                              hipStream_t stream) {
    const float* A  = (const float*)d_in[0];
    const float* Bf = (const float*)d_in[1];
    float* out = (float*)d_out;
    char* ws = (char*)d_ws;

    float* resp = (float*)ws;                                   // 256 KB
    int*   kp   = (int*)(ws + 262144);                          // 4 KB
    float* dn   = (float*)(ws + 266240);                        // 4 KB
    unsigned long long* minkey = (unsigned long long*)(ws + 270336); // 8 KB
    uint4* frag = (uint4*)(ws + 278528);                        // 2 MB

    hipMemsetAsync(minkey, 0xFF, BDIM * KKP * sizeof(unsigned long long), stream);
    resp_kernel<<<BDIM * HWDIM / 256, 256, 0, stream>>>(A, resp);
    argmax_kernel<<<BDIM * KKP, 64, 0, stream>>>(resp, kp);
    convert_kernel<<<BDIM * 16, 256, 0, stream>>>(A, kp, frag, dn);
    dist_mfma_kernel<<<dim3(256, BDIM), 512, 0, stream>>>(frag, Bf, dn, minkey);
    finalize_kernel<<<BDIM, KKP, 0, stream>>>(minkey, kp, out);
}